// Round 2
// baseline (127.652 us; speedup 1.0000x reference)
//
#include <hip/hip_runtime.h>

// B=524288 independent attentions over [S=10, D=6].
// out[b,q] = sum_k softmax_k(score[q,k]) * vsum[k]
// score[q,k] = t_q . x_k + a_k  (q-constant terms cancel in softmax)
//   t_q[dp]  = sum_d x_q[d] G[d][dp],  G = Wq^T Wk
//   a_k      = w . x_k,                w  = bq^T Wk
//   vsum[k]  = wvs . x_k + bvs,        wvs[d] = sum_e Wv[e][d], bvs = sum_e bv[e]
// ws layout (floats): [0..35] G row-major, [36..41] w, [42..47] wvs, [48] bvs

#define NB 524288
#define S 10
#define D 6
#define TPB 256      // threads per block
#define EPB 128      // elements per block (2 threads per element)
#define ROW 61       // padded LDS row stride in floats (gcd(61,32)=1 -> conflict-free)

__global__ void precompute_kernel(const float* __restrict__ Wk, const float* __restrict__ bk,
                                  const float* __restrict__ Wq, const float* __restrict__ bq,
                                  const float* __restrict__ Wv, const float* __restrict__ bv,
                                  float* __restrict__ ws) {
    int t = threadIdx.x;
    if (t < 36) {
        int d = t / 6, dp = t % 6;
        float g = 0.f;
        for (int e = 0; e < D; ++e) g += Wq[e * D + d] * Wk[e * D + dp];
        ws[t] = g;
    } else if (t < 42) {
        int dp = t - 36;
        float s = 0.f;
        for (int e = 0; e < D; ++e) s += bq[e] * Wk[e * D + dp];
        ws[t] = s;
    } else if (t < 48) {
        int d = t - 42;
        float s = 0.f;
        for (int e = 0; e < D; ++e) s += Wv[e * D + d];
        ws[t] = s;
    } else if (t == 48) {
        float s = 0.f;
        for (int e = 0; e < D; ++e) s += bv[e];
        ws[t] = s;
    }
}

__global__ __launch_bounds__(TPB, 5) void attn_kernel(const float* __restrict__ x,
                                                      const float* __restrict__ ws,
                                                      float* __restrict__ out) {
    __shared__ float xs[EPB * ROW];
    const int t = threadIdx.x;
    const int blk = blockIdx.x;

    // Wave-uniform constants -> s_load / SGPR resident
    float G[36], w[6], wvs[6];
    #pragma unroll
    for (int i = 0; i < 36; ++i) G[i] = ws[i];
    #pragma unroll
    for (int i = 0; i < 6; ++i) w[i] = ws[36 + i];
    #pragma unroll
    for (int i = 0; i < 6; ++i) wvs[i] = ws[42 + i];
    const float bvs = ws[48];

    // Coalesced global -> LDS staging: 128 elems * 15 float4 = 1920 float4
    const float4* xg = (const float4*)x + (size_t)blk * (EPB * 15);
    #pragma unroll
    for (int i = 0; i < 8; ++i) {
        int f = t + TPB * i;
        if (f < EPB * 15) {
            float4 v = xg[f];
            int e = f / 15, sub = f - e * 15;
            float* dst = &xs[e * ROW + sub * 4];
            dst[0] = v.x; dst[1] = v.y; dst[2] = v.z; dst[3] = v.w;
        }
    }
    __syncthreads();

    const int e = t >> 1;     // local element
    const int h = t & 1;      // which half of the 10 queries
    const float* xe = &xs[e * ROW];

    // t_q for this thread's 5 queries
    float tq[5][6];
    #pragma unroll
    for (int j = 0; j < 5; ++j) {
        int q = h * 5 + j;
        float xq[6];
        #pragma unroll
        for (int d = 0; d < 6; ++d) xq[d] = xe[q * 6 + d];
        #pragma unroll
        for (int dp = 0; dp < 6; ++dp) {
            float s = 0.f;
            #pragma unroll
            for (int d = 0; d < 6; ++d) s += xq[d] * G[d * 6 + dp];
            tq[j][dp] = s;
        }
    }

    float num[5] = {0.f, 0.f, 0.f, 0.f, 0.f};
    float den[5] = {0.f, 0.f, 0.f, 0.f, 0.f};
    #pragma unroll
    for (int k = 0; k < S; ++k) {
        float xk[6];
        #pragma unroll
        for (int d = 0; d < 6; ++d) xk[d] = xe[k * 6 + d];
        float a = 0.f, vk = bvs;
        #pragma unroll
        for (int d = 0; d < 6; ++d) { a += w[d] * xk[d]; vk += wvs[d] * xk[d]; }
        #pragma unroll
        for (int j = 0; j < 5; ++j) {
            float s = a;
            #pragma unroll
            for (int d = 0; d < 6; ++d) s += tq[j][d] * xk[d];
            float ex = __expf(s);
            den[j] += ex;
            num[j] += ex * vk;
        }
    }

    // Thread's 5 outputs are contiguous: out flat idx = blk*1280 + t*5 + j
    float* op = out + (size_t)blk * (EPB * S) + t * 5;
    #pragma unroll
    for (int j = 0; j < 5; ++j) op[j] = num[j] * __builtin_amdgcn_rcpf(den[j]);
}

extern "C" void kernel_launch(void* const* d_in, const int* in_sizes, int n_in,
                              void* d_out, int out_size, void* d_ws, size_t ws_size,
                              hipStream_t stream) {
    const float* x  = (const float*)d_in[0];
    const float* Wk = (const float*)d_in[1];
    const float* bk = (const float*)d_in[2];
    const float* Wq = (const float*)d_in[3];
    const float* bq = (const float*)d_in[4];
    const float* Wv = (const float*)d_in[5];
    const float* bv = (const float*)d_in[6];
    float* out = (float*)d_out;
    float* ws  = (float*)d_ws;

    precompute_kernel<<<1, 64, 0, stream>>>(Wk, bk, Wq, bq, Wv, bv, ws);
    attn_kernel<<<NB / EPB, TPB, 0, stream>>>(x, ws, out);
}

// Round 3
// 43.861 us; speedup vs baseline: 2.9103x; 2.9103x over previous
//
#include <hip/hip_runtime.h>

// B=524288 independent attentions over [S=10, D=6].
// out[b,q] = sum_k softmax_k(score[q,k]) * vsum[k]
// score[q,k] = t_q . x_k + a_k  (q-constant terms cancel in softmax)
//   t_q[dp]  = sum_d x_q[d] G[d][dp],  G = Wq^T Wk
//   a_k      = w . x_k,                w  = bq^T Wk
//   vsum[k]  = wvs . x_k + bvs,        wvs[d] = sum_e Wv[e][d], bvs = sum_e bv[e]
// ws layout (floats): [0..35] G row-major, [36..41] w, [42..47] wvs, [48] bvs

#define NB 524288
#define S 10
#define D 6
#define TPB 256      // threads per block
#define EPB 128      // elements per block (2 threads per element)
#define ROW 61       // padded LDS row stride in floats (gcd(61,32)=1 -> conflict-free)

__global__ void precompute_kernel(const float* __restrict__ Wk, const float* __restrict__ bk,
                                  const float* __restrict__ Wq, const float* __restrict__ bq,
                                  const float* __restrict__ Wv, const float* __restrict__ bv,
                                  float* __restrict__ ws) {
    int t = threadIdx.x;
    if (t < 36) {
        int d = t / 6, dp = t % 6;
        float g = 0.f;
        for (int e = 0; e < D; ++e) g += Wq[e * D + d] * Wk[e * D + dp];
        ws[t] = g;
    } else if (t < 42) {
        int dp = t - 36;
        float s = 0.f;
        for (int e = 0; e < D; ++e) s += bq[e] * Wk[e * D + dp];
        ws[t] = s;
    } else if (t < 48) {
        int d = t - 42;
        float s = 0.f;
        for (int e = 0; e < D; ++e) s += Wv[e * D + d];
        ws[t] = s;
    } else if (t == 48) {
        float s = 0.f;
        for (int e = 0; e < D; ++e) s += bv[e];
        ws[t] = s;
    }
}

// NOTE: launch_bounds (256,4) = 128-VGPR budget. (256,5) in R1 squeezed the
// allocator to 48 VGPRs -> ~290 MB of scratch spill traffic (WRITE_SIZE 311 MB
// vs 21 MB ideal). Kernel needs ~80 VGPRs; 4 blocks/CU is plenty.
__global__ __launch_bounds__(TPB, 4) void attn_kernel(const float* __restrict__ x,
                                                      const float* __restrict__ ws,
                                                      float* __restrict__ out) {
    __shared__ float xs[EPB * ROW];
    const int t = threadIdx.x;
    const int blk = blockIdx.x;

    // Wave-uniform constants -> s_load / SGPR resident
    float G[36], w[6], wvs[6];
    #pragma unroll
    for (int i = 0; i < 36; ++i) G[i] = ws[i];
    #pragma unroll
    for (int i = 0; i < 6; ++i) w[i] = ws[36 + i];
    #pragma unroll
    for (int i = 0; i < 6; ++i) wvs[i] = ws[42 + i];
    const float bvs = ws[48];

    // Coalesced global -> LDS staging: 128 elems * 15 float4 = 1920 float4
    const float4* xg = (const float4*)x + (size_t)blk * (EPB * 15);
    #pragma unroll
    for (int i = 0; i < 8; ++i) {
        int f = t + TPB * i;
        if (f < EPB * 15) {
            float4 v = xg[f];
            int e = f / 15, sub = f - e * 15;
            float* dst = &xs[e * ROW + sub * 4];
            dst[0] = v.x; dst[1] = v.y; dst[2] = v.z; dst[3] = v.w;
        }
    }
    __syncthreads();

    const int e = t >> 1;     // local element
    const int h = t & 1;      // which half of the 10 queries
    const float* xe = &xs[e * ROW];

    // t_q for this thread's 5 queries
    float tq[5][6];
    #pragma unroll
    for (int j = 0; j < 5; ++j) {
        int q = h * 5 + j;
        float xq[6];
        #pragma unroll
        for (int d = 0; d < 6; ++d) xq[d] = xe[q * 6 + d];
        #pragma unroll
        for (int dp = 0; dp < 6; ++dp) {
            float s = 0.f;
            #pragma unroll
            for (int d = 0; d < 6; ++d) s += xq[d] * G[d * 6 + dp];
            tq[j][dp] = s;
        }
    }

    float num[5] = {0.f, 0.f, 0.f, 0.f, 0.f};
    float den[5] = {0.f, 0.f, 0.f, 0.f, 0.f};
    #pragma unroll
    for (int k = 0; k < S; ++k) {
        float xk[6];
        #pragma unroll
        for (int d = 0; d < 6; ++d) xk[d] = xe[k * 6 + d];
        float a = 0.f, vk = bvs;
        #pragma unroll
        for (int d = 0; d < 6; ++d) { a += w[d] * xk[d]; vk += wvs[d] * xk[d]; }
        #pragma unroll
        for (int j = 0; j < 5; ++j) {
            float s = a;
            #pragma unroll
            for (int d = 0; d < 6; ++d) s += tq[j][d] * xk[d];
            float ex = __expf(s);
            den[j] += ex;
            num[j] += ex * vk;
        }
    }

    // Thread's 5 outputs are contiguous: out flat idx = blk*1280 + t*5 + j
    float* op = out + (size_t)blk * (EPB * S) + t * 5;
    #pragma unroll
    for (int j = 0; j < 5; ++j) op[j] = num[j] * __builtin_amdgcn_rcpf(den[j]);
}

extern "C" void kernel_launch(void* const* d_in, const int* in_sizes, int n_in,
                              void* d_out, int out_size, void* d_ws, size_t ws_size,
                              hipStream_t stream) {
    const float* x  = (const float*)d_in[0];
    const float* Wk = (const float*)d_in[1];
    const float* bk = (const float*)d_in[2];
    const float* Wq = (const float*)d_in[3];
    const float* bq = (const float*)d_in[4];
    const float* Wv = (const float*)d_in[5];
    const float* bv = (const float*)d_in[6];
    float* out = (float*)d_out;
    float* ws  = (float*)d_ws;

    precompute_kernel<<<1, 64, 0, stream>>>(Wk, bk, Wq, bq, Wv, bv, ws);
    attn_kernel<<<NB / EPB, TPB, 0, stream>>>(x, ws, out);
}